// Round 1
// baseline (2282.057 us; speedup 1.0000x reference)
//
#include <hip/hip_runtime.h>
#include <cmath>

#define NTOT 524288
#define KC   256
#define DD   128

// ---------------- prep: normalize codebook -> e_t[d][c] in ws, zero prob accum ----------------
__global__ __launch_bounds__(64) void vq_prep(const float* __restrict__ emb,
                                              float* __restrict__ et,
                                              float* __restrict__ pacc_g) {
  const int c = blockIdx.x;
  const int l = threadIdx.x;
  const float a = emb[c * DD + l];
  const float b = emb[c * DD + 64 + l];
  float s = a * a + b * b;
#pragma unroll
  for (int m = 32; m >= 1; m >>= 1) s += __shfl_xor(s, m, 64);
  const float inv = 1.0f / fmaxf(sqrtf(s), 1e-12f);
  et[l * KC + c] = a * inv;
  et[(l + 64) * KC + c] = b * inv;
  if (l == 0) pacc_g[c] = 0.0f;
}

// ---------------- main: dots + argmax (+fp64 tie refine) + softmax accum + gather ----------------
__global__ __launch_bounds__(256, 4) void vq_main(
    const float* __restrict__ z, const float* __restrict__ emb,
    const float* __restrict__ et, const float* __restrict__ lsp,
    float* __restrict__ zq, float* __restrict__ oidx, float* __restrict__ pacc_g) {
  __shared__ __align__(16) float zt[16][68];   // [dd][row], stride 68 -> 16B aligned rows, conflict-free reads
  __shared__ float nrm2[64];
  __shared__ float pp[KC];

  const int t    = threadIdx.x;
  const int tx   = t & 31;        // code group: codes tx*8..tx*8+7
  const int ty   = t >> 5;        // row group: rows ty*8..ty*8+7 (0..7)
  const int srow = t >> 2;        // staging row 0..63
  const int sq   = t & 3;         // staging quad
  const int lane = t & 63;
  const int halfbase = lane & 32; // first lane of my 32-lane half

  const float lscale = lsp[0];

  float pacc[8];
#pragma unroll
  for (int j = 0; j < 8; ++j) pacc[j] = 0.0f;

  for (int tile = blockIdx.x; tile < (NTOT / 64); tile += gridDim.x) {
    const int r0 = tile * 64;
    float acc[8][8];
#pragma unroll
    for (int i = 0; i < 8; ++i)
#pragma unroll
      for (int j = 0; j < 8; ++j) acc[i][j] = 0.0f;
    float nl = 0.0f;
    if (t < 64) nrm2[t] = 0.0f;

    for (int ch = 0; ch < 8; ++ch) {
      const int d0 = ch * 16;
      const float4 v = *(const float4*)(z + (size_t)(r0 + srow) * DD + d0 + sq * 4);
      nl += v.x * v.x + v.y * v.y + v.z * v.z + v.w * v.w;
      __syncthreads();            // prev chunk's reads done
      zt[sq * 4 + 0][srow] = v.x;
      zt[sq * 4 + 1][srow] = v.y;
      zt[sq * 4 + 2][srow] = v.z;
      zt[sq * 4 + 3][srow] = v.w;
      __syncthreads();            // this chunk's writes visible
#pragma unroll
      for (int dd = 0; dd < 16; ++dd) {
        const float4 e0 = *(const float4*)(et + (size_t)(d0 + dd) * KC + tx * 8);
        const float4 e1 = *(const float4*)(et + (size_t)(d0 + dd) * KC + tx * 8 + 4);
        const float4 za = *(const float4*)(&zt[dd][ty * 8]);
        const float4 zb = *(const float4*)(&zt[dd][ty * 8 + 4]);
        const float zr[8] = {za.x, za.y, za.z, za.w, zb.x, zb.y, zb.z, zb.w};
        const float er[8] = {e0.x, e0.y, e0.z, e0.w, e1.x, e1.y, e1.z, e1.w};
#pragma unroll
        for (int i = 0; i < 8; ++i)
#pragma unroll
          for (int j = 0; j < 8; ++j) acc[i][j] = fmaf(zr[i], er[j], acc[i][j]);
      }
    }
    atomicAdd(&nrm2[srow], nl);
    __syncthreads();

    // epilogue: one 32-lane half handles one row at a time (8 rows per half)
#pragma unroll 1
    for (int i = 0; i < 8; ++i) {
      const int r = r0 + ty * 8 + i;
      const float inv = lscale / fmaxf(sqrtf(nrm2[ty * 8 + i]), 1e-12f);
      float l8[8];
#pragma unroll
      for (int j = 0; j < 8; ++j) l8[j] = acc[i][j] * inv;

      // top-1 (first-occurrence tie rule: smaller index wins on equality)
      float m1 = l8[0];
      int i1 = tx * 8;
#pragma unroll
      for (int j = 1; j < 8; ++j)
        if (l8[j] > m1) { m1 = l8[j]; i1 = tx * 8 + j; }
#pragma unroll
      for (int s = 16; s >= 1; s >>= 1) {
        const float om = __shfl_xor(m1, s, 64);
        const int   oi = __shfl_xor(i1, s, 64);
        if (om > m1 || (om == m1 && oi < i1)) { m1 = om; i1 = oi; }
      }
      // top-2 (excluding global argmax)
      float m2 = -3.0e38f;
      int iy2 = 0;
#pragma unroll
      for (int j = 0; j < 8; ++j) {
        const int c = tx * 8 + j;
        if (c != i1 && l8[j] > m2) { m2 = l8[j]; iy2 = c; }
      }
#pragma unroll
      for (int s = 16; s >= 1; s >>= 1) {
        const float om = __shfl_xor(m2, s, 64);
        const int   oi = __shfl_xor(iy2, s, 64);
        if (om > m2 || (om == m2 && oi < iy2)) { m2 = om; iy2 = oi; }
      }
      // fp64 refinement for near-ties (uniform per half)
      if (m1 - m2 < 1.0e-3f) {
        if (tx == 0) {
          const float* e1p = emb + (size_t)i1 * DD;
          const float* e2p = emb + (size_t)iy2 * DD;
          const float* zp  = z + (size_t)r * DD;
          double s1 = 0.0, s2 = 0.0, q1 = 0.0, q2 = 0.0;
#pragma unroll 1
          for (int d = 0; d < DD; ++d) {
            const double zd = zp[d];
            const double a = e1p[d];
            const double b = e2p[d];
            s1 += zd * a; s2 += zd * b; q1 += a * a; q2 += b * b;
          }
          const double v1 = s1 / sqrt(q1);
          const double v2 = s2 / sqrt(q2);
          if (v2 > v1 || (v2 == v1 && iy2 < i1)) i1 = iy2;
        }
        i1 = __shfl(i1, halfbase, 64);
      }
      // softmax partial sums for avg_probs
      float se = 0.0f;
      float pr[8];
#pragma unroll
      for (int j = 0; j < 8; ++j) { pr[j] = expf(l8[j] - m1); se += pr[j]; }
#pragma unroll
      for (int s = 16; s >= 1; s >>= 1) se += __shfl_xor(se, s, 64);
      const float rs = 1.0f / se;
#pragma unroll
      for (int j = 0; j < 8; ++j) pacc[j] = fmaf(pr[j], rs, pacc[j]);

      // outputs: gather embeddings[i1] -> z_q row; index as float
      const float4 ev = *(const float4*)(emb + (size_t)i1 * DD + tx * 4);
      *(float4*)(zq + (size_t)r * DD + tx * 4) = ev;
      if (tx == 0) oidx[r] = (float)i1;
    }
    __syncthreads();
  }

  // block-level avg_probs reduction -> one global atomic per code
  pp[t] = 0.0f;
  __syncthreads();
#pragma unroll
  for (int j = 0; j < 8; ++j) atomicAdd(&pp[tx * 8 + j], pacc[j]);
  __syncthreads();
  atomicAdd(&pacc_g[t], pp[t]);
}

// ---------------- perplexity ----------------
__global__ __launch_bounds__(256) void vq_perp(const float* __restrict__ pacc_g,
                                               float* __restrict__ outp) {
  __shared__ double red[256];
  const int t = threadIdx.x;
  const double p = (double)pacc_g[t] * (1.0 / (double)NTOT);
  red[t] = p * log(p + 1e-10);
  __syncthreads();
  for (int s = 128; s > 0; s >>= 1) {
    if (t < s) red[t] += red[t + s];
    __syncthreads();
  }
  if (t == 0) outp[0] = (float)exp(-red[0]);
}

extern "C" void kernel_launch(void* const* d_in, const int* in_sizes, int n_in,
                              void* d_out, int out_size, void* d_ws, size_t ws_size,
                              hipStream_t stream) {
  const float* z   = (const float*)d_in[0];
  const float* emb = (const float*)d_in[1];
  const float* lsp = (const float*)d_in[2];

  float* ws_probs = (float*)d_ws;            // [256] prob accumulator
  float* ws_et    = ws_probs + KC;           // [128][256] normalized transposed codebook

  float* zq    = (float*)d_out;              // [N,128]
  float* oidx  = zq + (size_t)NTOT * DD;     // [N] indices as float
  float* operp = oidx + NTOT;                // [1]

  vq_prep<<<KC, 64, 0, stream>>>(emb, ws_et, ws_probs);
  vq_main<<<2048, 256, 0, stream>>>(z, emb, ws_et, lsp, zq, oidx, ws_probs);
  vq_perp<<<1, 256, 0, stream>>>(ws_probs, operp);
}

// Round 2
// 1309.711 us; speedup vs baseline: 1.7424x; 1.7424x over previous
//
#include <hip/hip_runtime.h>
#include <cmath>

#define NTOT 524288
#define KC   256
#define DD   128

// ---------------- prep: normalize codebook -> e_t[d][c] in ws, zero prob accum ----------------
__global__ __launch_bounds__(64) void vq_prep(const float* __restrict__ emb,
                                              float* __restrict__ et,
                                              float* __restrict__ pacc_g) {
  const int c = blockIdx.x;
  const int l = threadIdx.x;
  const float a = emb[c * DD + l];
  const float b = emb[c * DD + 64 + l];
  float s = a * a + b * b;
#pragma unroll
  for (int m = 32; m >= 1; m >>= 1) s += __shfl_xor(s, m, 64);
  const float inv = 1.0f / fmaxf(sqrtf(s), 1e-12f);
  et[l * KC + c] = a * inv;
  et[(l + 64) * KC + c] = b * inv;
  if (l == 0) pacc_g[c] = 0.0f;
}

// ---------------- main: dots + argmax (+fp64 tie refine) + softmax accum + gather ----------------
__global__ __launch_bounds__(256, 4) void vq_main(
    const float* __restrict__ z, const float* __restrict__ emb,
    const float* __restrict__ et, const float* __restrict__ lsp,
    float* __restrict__ zq, float* __restrict__ oidx, float* __restrict__ pacc_g) {
  __shared__ __align__(16) float zt[16][68];   // [dd][row], stride 68 -> 16B aligned rows, conflict-free reads
  __shared__ float nrm2[64];
  __shared__ float pp[KC];

  const int t    = threadIdx.x;
  const int tx   = t & 31;        // code group: codes tx*8..tx*8+7
  const int ty   = t >> 5;        // row group: rows ty*8..ty*8+7 (0..7)
  const int srow = t >> 2;        // staging row 0..63
  const int sq   = t & 3;         // staging quad
  const int lane = t & 63;
  const int halfbase = lane & 32; // first lane of my 32-lane half

  const float lscale = lsp[0];

  float pacc[8];
#pragma unroll
  for (int j = 0; j < 8; ++j) pacc[j] = 0.0f;

  for (int tile = blockIdx.x; tile < (NTOT / 64); tile += gridDim.x) {
    const int r0 = tile * 64;
    float acc[8][8];
#pragma unroll
    for (int i = 0; i < 8; ++i)
#pragma unroll
      for (int j = 0; j < 8; ++j) acc[i][j] = 0.0f;
    float nl = 0.0f;
    if (t < 64) nrm2[t] = 0.0f;

    for (int ch = 0; ch < 8; ++ch) {
      const int d0 = ch * 16;
      const float4 v = *(const float4*)(z + (size_t)(r0 + srow) * DD + d0 + sq * 4);
      nl += v.x * v.x + v.y * v.y + v.z * v.z + v.w * v.w;
      __syncthreads();            // prev chunk's reads done
      zt[sq * 4 + 0][srow] = v.x;
      zt[sq * 4 + 1][srow] = v.y;
      zt[sq * 4 + 2][srow] = v.z;
      zt[sq * 4 + 3][srow] = v.w;
      __syncthreads();            // this chunk's writes visible
#pragma unroll
      for (int dd = 0; dd < 16; ++dd) {
        const float4 e0 = *(const float4*)(et + (size_t)(d0 + dd) * KC + tx * 8);
        const float4 e1 = *(const float4*)(et + (size_t)(d0 + dd) * KC + tx * 8 + 4);
        const float4 za = *(const float4*)(&zt[dd][ty * 8]);
        const float4 zb = *(const float4*)(&zt[dd][ty * 8 + 4]);
        const float zr[8] = {za.x, za.y, za.z, za.w, zb.x, zb.y, zb.z, zb.w};
        const float er[8] = {e0.x, e0.y, e0.z, e0.w, e1.x, e1.y, e1.z, e1.w};
#pragma unroll
        for (int i = 0; i < 8; ++i)
#pragma unroll
          for (int j = 0; j < 8; ++j) acc[i][j] = fmaf(zr[i], er[j], acc[i][j]);
      }
    }
    atomicAdd(&nrm2[srow], nl);
    __syncthreads();

    // epilogue: one 32-lane half handles one row at a time (8 rows per half).
    // FULLY UNROLLED: runtime-indexed acc[i][...] demotes the accumulator
    // array to scratch (R1: 6.6 GB HBM writes, VGPR=64, 2050 us).
#pragma unroll
    for (int i = 0; i < 8; ++i) {
      const int r = r0 + ty * 8 + i;
      const float inv = lscale / fmaxf(sqrtf(nrm2[ty * 8 + i]), 1e-12f);
      float l8[8];
#pragma unroll
      for (int j = 0; j < 8; ++j) l8[j] = acc[i][j] * inv;

      // top-1 (first-occurrence tie rule: smaller index wins on equality)
      float m1 = l8[0];
      int i1 = tx * 8;
#pragma unroll
      for (int j = 1; j < 8; ++j)
        if (l8[j] > m1) { m1 = l8[j]; i1 = tx * 8 + j; }
#pragma unroll
      for (int s = 16; s >= 1; s >>= 1) {
        const float om = __shfl_xor(m1, s, 64);
        const int   oi = __shfl_xor(i1, s, 64);
        if (om > m1 || (om == m1 && oi < i1)) { m1 = om; i1 = oi; }
      }
      // top-2 (excluding global argmax)
      float m2 = -3.0e38f;
      int iy2 = 0;
#pragma unroll
      for (int j = 0; j < 8; ++j) {
        const int c = tx * 8 + j;
        if (c != i1 && l8[j] > m2) { m2 = l8[j]; iy2 = c; }
      }
#pragma unroll
      for (int s = 16; s >= 1; s >>= 1) {
        const float om = __shfl_xor(m2, s, 64);
        const int   oi = __shfl_xor(iy2, s, 64);
        if (om > m2 || (om == m2 && oi < iy2)) { m2 = om; iy2 = oi; }
      }
      // fp64 refinement for near-ties (uniform per half)
      if (m1 - m2 < 1.0e-3f) {
        if (tx == 0) {
          const float* e1p = emb + (size_t)i1 * DD;
          const float* e2p = emb + (size_t)iy2 * DD;
          const float* zp  = z + (size_t)r * DD;
          double s1 = 0.0, s2 = 0.0, q1 = 0.0, q2 = 0.0;
#pragma unroll 1
          for (int d = 0; d < DD; ++d) {
            const double zd = zp[d];
            const double a = e1p[d];
            const double b = e2p[d];
            s1 += zd * a; s2 += zd * b; q1 += a * a; q2 += b * b;
          }
          const double v1 = s1 / sqrt(q1);
          const double v2 = s2 / sqrt(q2);
          if (v2 > v1 || (v2 == v1 && iy2 < i1)) i1 = iy2;
        }
        i1 = __shfl(i1, halfbase, 64);
      }
      // softmax partial sums for avg_probs
      float se = 0.0f;
      float pr[8];
#pragma unroll
      for (int j = 0; j < 8; ++j) { pr[j] = expf(l8[j] - m1); se += pr[j]; }
#pragma unroll
      for (int s = 16; s >= 1; s >>= 1) se += __shfl_xor(se, s, 64);
      const float rs = 1.0f / se;
#pragma unroll
      for (int j = 0; j < 8; ++j) pacc[j] = fmaf(pr[j], rs, pacc[j]);

      // outputs: gather embeddings[i1] -> z_q row; index as float
      const float4 ev = *(const float4*)(emb + (size_t)i1 * DD + tx * 4);
      *(float4*)(zq + (size_t)r * DD + tx * 4) = ev;
      if (tx == 0) oidx[r] = (float)i1;
    }
    __syncthreads();
  }

  // block-level avg_probs reduction -> one global atomic per code
  pp[t] = 0.0f;
  __syncthreads();
#pragma unroll
  for (int j = 0; j < 8; ++j) atomicAdd(&pp[tx * 8 + j], pacc[j]);
  __syncthreads();
  atomicAdd(&pacc_g[t], pp[t]);
}

// ---------------- perplexity ----------------
__global__ __launch_bounds__(256) void vq_perp(const float* __restrict__ pacc_g,
                                               float* __restrict__ outp) {
  __shared__ double red[256];
  const int t = threadIdx.x;
  const double p = (double)pacc_g[t] * (1.0 / (double)NTOT);
  red[t] = p * log(p + 1e-10);
  __syncthreads();
  for (int s = 128; s > 0; s >>= 1) {
    if (t < s) red[t] += red[t + s];
    __syncthreads();
  }
  if (t == 0) outp[0] = (float)exp(-red[0]);
}

extern "C" void kernel_launch(void* const* d_in, const int* in_sizes, int n_in,
                              void* d_out, int out_size, void* d_ws, size_t ws_size,
                              hipStream_t stream) {
  const float* z   = (const float*)d_in[0];
  const float* emb = (const float*)d_in[1];
  const float* lsp = (const float*)d_in[2];

  float* ws_probs = (float*)d_ws;            // [256] prob accumulator
  float* ws_et    = ws_probs + KC;           // [128][256] normalized transposed codebook

  float* zq    = (float*)d_out;              // [N,128]
  float* oidx  = zq + (size_t)NTOT * DD;     // [N] indices as float
  float* operp = oidx + NTOT;                // [1]

  vq_prep<<<KC, 64, 0, stream>>>(emb, ws_et, ws_probs);
  vq_main<<<2048, 256, 0, stream>>>(z, emb, ws_et, lsp, zq, oidx, ws_probs);
  vq_perp<<<1, 256, 0, stream>>>(ws_probs, operp);
}